// Round 14
// baseline (141.987 us; speedup 1.0000x reference)
//
#include <hip/hip_runtime.h>
#include <math.h>

#define B_ 8
#define N_ 1024
#define C_ 320
#define H_ 5
#define D_ 64
#define M_ (B_*N_)

typedef unsigned short ushort_t;
typedef _Float16 half_t;
typedef __attribute__((ext_vector_type(2))) _Float16 h2;
typedef __attribute__((ext_vector_type(8))) _Float16 f16x8;
typedef __attribute__((ext_vector_type(4))) float f32x4;

// fp32 -> fp16 RNE, 1 VALU op (v_cvt_f16_f32)
__device__ __forceinline__ ushort_t f2h(float f) {
  union { half_t h; ushort_t u; } c; c.h = (half_t)f; return c.u;
}
// 2x fp32 -> packed fp16x2 RTZ, 1 VALU op (v_cvt_pkrtz_f16_f32)
__device__ __forceinline__ unsigned pkrtz(float a, float b) {
  auto r = __builtin_amdgcn_cvt_pkrtz(a, b);
  union { decltype(r) v; unsigned u; } c; c.v = r; return c.u;
}

// ------- prep: weight fp16 conversion + LayerNorm, one launch -------
__global__ __launch_bounds__(256) void prep_kernel(
    const float* __restrict__ qkv_w, const float* __restrict__ proj_w,
    const float* __restrict__ x, const float* __restrict__ gamma,
    const float* __restrict__ beta,
    ushort_t* __restrict__ wqb, ushort_t* __restrict__ wpb,
    ushort_t* __restrict__ xnb) {
  int bid = blockIdx.x;
  int tid = threadIdx.x;
  if (bid < 200) {
    const float* src = bid < 150 ? qkv_w : proj_w;
    ushort_t* dst    = bid < 150 ? wqb   : wpb;
    int base = (bid < 150 ? bid : bid - 150) * 2048;
    int idx = base + tid*8;
    float4 x0 = *(const float4*)(src+idx);
    float4 x1 = *(const float4*)(src+idx+4);
    unsigned pk[4] = {pkrtz(x0.x,x0.y), pkrtz(x0.z,x0.w),
                      pkrtz(x1.x,x1.y), pkrtz(x1.z,x1.w)};
    *(uint4*)(dst+idx) = *(const uint4*)pk;
  } else {
    int row = (bid - 200)*4 + (tid >> 6);
    int lane = tid & 63;
    const float* xr = x + (long)row * C_;
    float vals[5];
    float s = 0.f, ss = 0.f;
#pragma unroll
    for (int j = 0; j < 5; ++j) {
      float vv = xr[lane + 64*j];
      vals[j] = vv; s += vv; ss += vv*vv;
    }
#pragma unroll
    for (int o = 32; o > 0; o >>= 1) {
      s  += __shfl_xor(s, o, 64);
      ss += __shfl_xor(ss, o, 64);
    }
    float mean = s * (1.0f/C_);
    float var  = ss * (1.0f/C_) - mean*mean;
    float rstd = rsqrtf(var + 1e-5f);
    ushort_t* outr = xnb + (long)row * C_;
#pragma unroll
    for (int j = 0; j < 5; ++j) {
      int c = lane + 64*j;
      outr[c] = f2h((vals[j]-mean)*rstd*gamma[c] + beta[c]);
    }
  }
}

// ---------------- QKV GEMM via MFMA fp16: 128(M)x64(N) tile (r13-exact) -----
__global__ __launch_bounds__(256) void qkvm_kernel(const ushort_t* __restrict__ xnb,
    const ushort_t* __restrict__ wqb, const float* __restrict__ bias,
    ushort_t* __restrict__ q, ushort_t* __restrict__ k, ushort_t* __restrict__ vt) {
  __shared__ __align__(16) ushort_t As[2][128][72];
  __shared__ __align__(16) ushort_t Bs[2][64][72];
  __shared__ __align__(16) ushort_t Vs[64][136];
  int j0 = blockIdx.x * 64;
  int m0 = blockIdx.y * 128;
  int tid = threadIdx.x;
  int lane = tid & 63, wv = tid >> 6;
  int l16 = lane & 15, qd = lane >> 4;
  f32x4 acc[2][4];
#pragma unroll
  for (int i=0;i<2;++i)
#pragma unroll
    for (int j=0;j<4;++j) acc[i][j] = (f32x4){0.f,0.f,0.f,0.f};

  const ushort_t* agp = xnb + (long)m0*C_;
  const ushort_t* bgp = wqb + (long)j0*C_;

  // prologue: load K-step 0 to regs, write buf 0, barrier
  {
    uint4 rA[4], rB[2];
#pragma unroll
    for (int i = 0; i < 4; ++i) {
      int idx = tid + 256*i;
      int row = idx >> 3, c8 = (idx & 7) << 3;
      rA[i] = *(const uint4*)(agp + (long)row*C_ + c8);
    }
    {
      int idx = tid, row = idx >> 3, c8 = (idx & 7) << 3;
      rB[0] = *(const uint4*)(bgp + (long)row*C_ + c8);
      idx = tid + 256; row = idx >> 3; c8 = (idx & 7) << 3;
      rB[1] = *(const uint4*)(bgp + (long)row*C_ + c8);
    }
#pragma unroll
    for (int i = 0; i < 4; ++i) {
      int idx = tid + 256*i;
      int row = idx >> 3, c8 = (idx & 7) << 3;
      *(uint4*)&As[0][row][c8] = rA[i];
    }
    {
      int idx = tid, row = idx >> 3, c8 = (idx & 7) << 3;
      *(uint4*)&Bs[0][row][c8] = rB[0];
      idx = tid + 256; row = idx >> 3; c8 = (idx & 7) << 3;
      *(uint4*)&Bs[0][row][c8] = rB[1];
    }
  }
  __syncthreads();

  for (int kt5 = 0; kt5 < 5; ++kt5) {
    const int cur = kt5 & 1, nxt = cur ^ 1;
    uint4 rA[4], rB[2];
    if (kt5 < 4) {
      int kn = kt5*64 + 64;
#pragma unroll
      for (int i = 0; i < 4; ++i) {
        int idx = tid + 256*i;
        int row = idx >> 3, c8 = (idx & 7) << 3;
        rA[i] = *(const uint4*)(agp + (long)row*C_ + kn + c8);
      }
      int idx = tid, row = idx >> 3, c8 = (idx & 7) << 3;
      rB[0] = *(const uint4*)(bgp + (long)row*C_ + kn + c8);
      idx = tid + 256; row = idx >> 3; c8 = (idx & 7) << 3;
      rB[1] = *(const uint4*)(bgp + (long)row*C_ + kn + c8);
    }
#pragma unroll
    for (int kb = 0; kb < 2; ++kb) {
      int ko = kb*32 + qd*8;
      f16x8 a0 = *(const f16x8*)&As[cur][wv*32 + l16][ko];
      f16x8 a1 = *(const f16x8*)&As[cur][wv*32 + 16 + l16][ko];
#pragma unroll
      for (int ct = 0; ct < 4; ++ct) {
        f16x8 b = *(const f16x8*)&Bs[cur][ct*16 + l16][ko];
        acc[0][ct] = __builtin_amdgcn_mfma_f32_16x16x32_f16(a0, b, acc[0][ct], 0,0,0);
        acc[1][ct] = __builtin_amdgcn_mfma_f32_16x16x32_f16(a1, b, acc[1][ct], 0,0,0);
      }
    }
    if (kt5 < 4) {
#pragma unroll
      for (int i = 0; i < 4; ++i) {
        int idx = tid + 256*i;
        int row = idx >> 3, c8 = (idx & 7) << 3;
        *(uint4*)&As[nxt][row][c8] = rA[i];
      }
      int idx = tid, row = idx >> 3, c8 = (idx & 7) << 3;
      *(uint4*)&Bs[nxt][row][c8] = rB[0];
      idx = tid + 256; row = idx >> 3; c8 = (idx & 7) << 3;
      *(uint4*)&Bs[nxt][row][c8] = rB[1];
    }
    __syncthreads();
  }
  int three = j0 / 320;
  int rembase = j0 - three*320;
  if (three < 2) {
    ushort_t* dst = three == 0 ? q : k;
    float scale = three == 0 ? 0.125f : 1.0f;
#pragma unroll
    for (int rt = 0; rt < 2; ++rt)
#pragma unroll
      for (int ct = 0; ct < 4; ++ct) {
        int rem = rembase + ct*16 + l16;
        int h = rem >> 6, dd = rem & 63;
        float bi = bias[j0 + ct*16 + l16];
#pragma unroll
        for (int r = 0; r < 4; ++r) {
          int m = m0 + wv*32 + rt*16 + qd*4 + r;
          int b = m >> 10, n = m & (N_-1);
          dst[(((long)b*H_ + h)*N_ + n)*D_ + dd] = f2h((acc[rt][ct][r] + bi) * scale);
        }
      }
  } else {
    int h = rembase >> 6;
#pragma unroll
    for (int rt = 0; rt < 2; ++rt)
#pragma unroll
      for (int ct = 0; ct < 4; ++ct) {
        float bi = bias[j0 + ct*16 + l16];
#pragma unroll
        for (int r = 0; r < 4; ++r) {
          int col = wv*32 + rt*16 + qd*4 + r;
          Vs[ct*16 + l16][col] = f2h(acc[rt][ct][r] + bi);
        }
      }
    __syncthreads();
    int b = m0 >> 10, n0b = m0 & (N_-1);
#pragma unroll
    for (int i = 0; i < 4; ++i) {
      int idx = tid + 256*i;
      int row = idx >> 4, c8 = (idx & 15) << 3;
      *(uint4*)(vt + (((long)b*H_ + h)*D_ + row)*N_ + n0b + c8) = *(const uint4*)&Vs[row][c8];
    }
  }
}

// ------- kb: K-blur factor precompute (qb slimmed: Q-blur moved into bsp) ---
// kb = alpha * w-blur of k along n (reflect). Bit-identical to old qb's ak.
__global__ __launch_bounds__(512) void kb_kernel(
    const ushort_t* __restrict__ kk, ushort_t* __restrict__ kb) {
  int bh = blockIdx.y;
  int h = bh % H_;
  int r = blockIdx.x*64 + (threadIdx.x >> 3);
  int d8 = (threadIdx.x & 7) << 3;
  float sigma = (float)(h + 1);
  float ei = -1.f / (2.f * sigma * sigma);
  float ga = expf(9.f*ei), gb = expf(4.f*ei), gc = expf(1.f*ei);
  float isum = 1.f / (2.f*(ga + gb + gc) + 1.f);
  float alpha = 0.1f * sigma;
  const float w[7] = {ga*isum, gb*isum, gc*isum, isum, gc*isum, gb*isum, ga*isum};
  const ushort_t* kb_base = kk + (long)bh*N_*D_ + d8;
  float ak[8] = {0,0,0,0,0,0,0,0};
#pragma unroll
  for (int t = 0; t < 7; ++t) {
    int p = r + t - 3;
    int rr = p < 0 ? -p : (p > N_-1 ? 2*(N_-1)-p : p);
    union { uint4 v; h2 hh[4]; } uk;
    uk.v = *(const uint4*)(kb_base + (long)rr*D_);
    float wt = w[t];
#pragma unroll
    for (int j = 0; j < 4; ++j) {
      ak[2*j]   += wt * (float)uk.hh[j].x;
      ak[2*j+1] += wt * (float)uk.hh[j].y;
    }
  }
  ushort_t pk[8];
#pragma unroll
  for (int j = 0; j < 8; ++j) pk[j] = f2h(ak[j] * alpha);
  *(uint4*)(kb + ((long)bh*N_ + r)*D_ + d8) = *(const uint4*)pk;
}

// blur one q-row fragment (8 fp16 at byte-col `off`) — same math as old qb.
__device__ __forceinline__ f16x8 blur_q8(const ushort_t* qbh, int R, int off,
                                         const float* w) {
  float a[8] = {0,0,0,0,0,0,0,0};
#pragma unroll
  for (int t = 0; t < 7; ++t) {
    int p = R + t - 3;
    int rr = p < 0 ? -p : (p > N_-1 ? 2*(N_-1)-p : p);
    union { uint4 v; h2 hh[4]; } u;
    u.v = *(const uint4*)(qbh + (long)rr*D_ + off);
    float wt = w[t];
#pragma unroll
    for (int j = 0; j < 4; ++j) {
      a[2*j]   += wt * (float)u.hh[j].x;
      a[2*j+1] += wt * (float)u.hh[j].y;
    }
  }
  union { ushort_t u[8]; f16x8 v; } r;
#pragma unroll
  for (int j = 0; j < 8; ++j) r.u[j] = f2h(a[j]);
  return r.v;
}

// ------- Flash fused logits + softmax + PV (v21: v19 + in-prologue Q-blur) --
// v19 core (32 q/wave, r7 chunk schedule) with blur(Q) fragments computed in
// the prologue (28 L2 loads + ~700 VALU once/block) instead of reading a
// materialized qbb buffer — removes half of the old qb kernel + the qbb
// round trip. Bit-identical math (same fp32 accum order, f2h RNE).
__global__ __launch_bounds__(256, 2) void bsp_kernel(
    const ushort_t* __restrict__ q,
    const ushort_t* __restrict__ kk, const ushort_t* __restrict__ kb,
    const ushort_t* __restrict__ vt, ushort_t* __restrict__ aob) {
  __shared__ __align__(16) ushort_t Ks[2][64][72];
  __shared__ __align__(16) ushort_t Bs[2][64][72];
  __shared__ __align__(16) ushort_t Vs[2][64][72];
  __shared__ __align__(16) ushort_t Pb[4][32][72];

  int lin = blockIdx.x;
  int lin2 = (lin & 7)*40 + (lin >> 3);   // bijective: 320 = 8*40
  int bh = lin2 >> 3;
  int qblk = lin2 & 7;
  int h = bh % H_;
  int bb = bh / H_;
  int tid = threadIdx.x;
  int wv = tid >> 6, lane = tid & 63;
  int l16 = lane & 15, qd = lane >> 4;
  int qbase = qblk*128 + wv*32;

  int srow = tid >> 3, sc8 = (tid & 7) << 3;
  const ushort_t* kgp = kk + (long)bh*N_*D_ + (long)srow*D_ + sc8;
  const ushort_t* bgp = kb + (long)bh*N_*D_ + (long)srow*D_ + sc8;
  const ushort_t* vgp = vt + (long)bh*D_*N_ + (long)srow*N_ + sc8;

  // blur weights (same derivation as kb_kernel; unscaled for Q side)
  float sigma = (float)(h + 1);
  float ei = -1.f / (2.f * sigma * sigma);
  float ga = expf(9.f*ei), gb = expf(4.f*ei), gc = expf(1.f*ei);
  float isum = 1.f / (2.f*(ga + gb + gc) + 1.f);
  const float w[7] = {ga*isum, gb*isum, gc*isum, isum, gc*isum, gb*isum, ga*isum};

  const ushort_t* qbh = q + (long)bh*N_*D_;
  long qoffA = ((long)qbase + l16)*D_ + qd*8;
  long qoffB = ((long)qbase + 16 + l16)*D_ + qd*8;
  f16x8 bqA0 = *(const f16x8*)(qbh + qoffA);
  f16x8 bqA1 = *(const f16x8*)(qbh + qoffA + 32);
  f16x8 bqB0 = *(const f16x8*)(qbh + qoffB);
  f16x8 bqB1 = *(const f16x8*)(qbh + qoffB + 32);
  f16x8 bqA2 = blur_q8(qbh, qbase + l16,      qd*8,      w);
  f16x8 bqA3 = blur_q8(qbh, qbase + l16,      qd*8 + 32, w);
  f16x8 bqB2 = blur_q8(qbh, qbase + 16 + l16, qd*8,      w);
  f16x8 bqB3 = blur_q8(qbh, qbase + 16 + l16, qd*8 + 32, w);

  ushort_t (*Pw)[72] = Pb[wv];
  float rsum0 = 0.f, rsum1 = 0.f;
  f32x4 oaA[4], oaB[4];
#pragma unroll
  for (int dt = 0; dt < 4; ++dt) {
    oaA[dt] = (f32x4){0.f,0.f,0.f,0.f};
    oaB[dt] = (f32x4){0.f,0.f,0.f,0.f};
  }

  *(uint4*)&Ks[0][srow][sc8]    = *(const uint4*)(kgp);
  *(uint4*)&Ks[0][srow+32][sc8] = *(const uint4*)(kgp + 32*D_);
  *(uint4*)&Bs[0][srow][sc8]    = *(const uint4*)(bgp);
  *(uint4*)&Bs[0][srow+32][sc8] = *(const uint4*)(bgp + 32*D_);
  *(uint4*)&Vs[0][srow][sc8]    = *(const uint4*)(vgp);
  *(uint4*)&Vs[0][srow+32][sc8] = *(const uint4*)(vgp + 32*N_);
  __syncthreads();

  for (int ch = 0; ch < 16; ++ch) {
    const int cur = ch & 1, nxt = cur ^ 1;
    uint4 gk0, gk1, gb0, gb1, gv0, gv1;
    if (ch < 15) {
      long c1 = (long)(ch + 1) * 64;
      gk0 = *(const uint4*)(kgp + c1*D_);
      gk1 = *(const uint4*)(kgp + (c1+32)*D_);
      gb0 = *(const uint4*)(bgp + c1*D_);
      gb1 = *(const uint4*)(bgp + (c1+32)*D_);
      gv0 = *(const uint4*)(vgp + c1);
      gv1 = *(const uint4*)(vgp + 32*N_ + c1);
    }
#pragma unroll
    for (int kt = 0; kt < 4; ++kt) {
      int r = kt*16 + l16;
      f16x8 a0 = *(const f16x8*)&Ks[cur][r][qd*8];
      f16x8 a1 = *(const f16x8*)&Ks[cur][r][qd*8 + 32];
      f16x8 a2 = *(const f16x8*)&Bs[cur][r][qd*8];
      f16x8 a3 = *(const f16x8*)&Bs[cur][r][qd*8 + 32];
      f32x4 s0 = (f32x4){0.f,0.f,0.f,0.f};
      f32x4 s1 = (f32x4){0.f,0.f,0.f,0.f};
      s0 = __builtin_amdgcn_mfma_f32_16x16x32_f16(a0, bqA0, s0, 0,0,0);
      s1 = __builtin_amdgcn_mfma_f32_16x16x32_f16(a0, bqB0, s1, 0,0,0);
      s0 = __builtin_amdgcn_mfma_f32_16x16x32_f16(a1, bqA1, s0, 0,0,0);
      s1 = __builtin_amdgcn_mfma_f32_16x16x32_f16(a1, bqB1, s1, 0,0,0);
      s0 = __builtin_amdgcn_mfma_f32_16x16x32_f16(a2, bqA2, s0, 0,0,0);
      s1 = __builtin_amdgcn_mfma_f32_16x16x32_f16(a2, bqB2, s1, 0,0,0);
      s0 = __builtin_amdgcn_mfma_f32_16x16x32_f16(a3, bqA3, s0, 0,0,0);
      s1 = __builtin_amdgcn_mfma_f32_16x16x32_f16(a3, bqB3, s1, 0,0,0);
      float e0 = __expf(s0[0]), e1 = __expf(s0[1]);
      float e2 = __expf(s0[2]), e3 = __expf(s0[3]);
      float f0 = __expf(s1[0]), f1 = __expf(s1[1]);
      float f2 = __expf(s1[2]), f3 = __expf(s1[3]);
      rsum0 += (e0 + e1) + (e2 + e3);
      rsum1 += (f0 + f1) + (f2 + f3);
      *(uint2*)&Pw[l16][kt*16 + qd*4]      = make_uint2(pkrtz(e0,e1), pkrtz(e2,e3));
      *(uint2*)&Pw[16 + l16][kt*16 + qd*4] = make_uint2(pkrtz(f0,f1), pkrtz(f2,f3));
    }
#pragma unroll
    for (int ks = 0; ks < 2; ++ks) {
      f16x8 af0 = *(const f16x8*)&Pw[l16][ks*32 + qd*8];
      f16x8 af1 = *(const f16x8*)&Pw[16 + l16][ks*32 + qd*8];
#pragma unroll
      for (int dt = 0; dt < 4; ++dt) {
        f16x8 bf = *(const f16x8*)&Vs[cur][dt*16 + l16][ks*32 + qd*8];
        oaA[dt] = __builtin_amdgcn_mfma_f32_16x16x32_f16(af0, bf, oaA[dt], 0,0,0);
        oaB[dt] = __builtin_amdgcn_mfma_f32_16x16x32_f16(af1, bf, oaB[dt], 0,0,0);
      }
    }
    if (ch < 15) {
      *(uint4*)&Ks[nxt][srow][sc8]    = gk0;
      *(uint4*)&Ks[nxt][srow+32][sc8] = gk1;
      *(uint4*)&Bs[nxt][srow][sc8]    = gb0;
      *(uint4*)&Bs[nxt][srow+32][sc8] = gb1;
      *(uint4*)&Vs[nxt][srow][sc8]    = gv0;
      *(uint4*)&Vs[nxt][srow+32][sc8] = gv1;
    }
    __syncthreads();
  }

  rsum0 += __shfl_xor(rsum0, 16, 64);
  rsum0 += __shfl_xor(rsum0, 32, 64);
  rsum1 += __shfl_xor(rsum1, 16, 64);
  rsum1 += __shfl_xor(rsum1, 32, 64);
  float rinv0 = 1.f / rsum0;
  float rinv1 = 1.f / rsum1;
  float rv0[4], rv1[4];
#pragma unroll
  for (int r = 0; r < 4; ++r) {
    rv0[r] = __shfl(rinv0, qd*4 + r, 64);
    rv1[r] = __shfl(rinv1, qd*4 + r, 64);
  }
#pragma unroll
  for (int dt = 0; dt < 4; ++dt)
#pragma unroll
    for (int r = 0; r < 4; ++r) {
      aob[((long)(bb*N_ + qbase + qd*4 + r))*C_ + h*64 + dt*16 + l16] =
          f2h(oaA[dt][r] * rv0[r]);
      aob[((long)(bb*N_ + qbase + 16 + qd*4 + r))*C_ + h*64 + dt*16 + l16] =
          f2h(oaB[dt][r] * rv1[r]);
    }
}

// ---------------- proj GEMM via MFMA fp16: 128(M)x64(N) tile (r13-exact) ----
__global__ __launch_bounds__(256) void projm_kernel(const ushort_t* __restrict__ aob,
    const ushort_t* __restrict__ wpb, const float* __restrict__ bias,
    float* __restrict__ out) {
  __shared__ __align__(16) ushort_t As[2][128][72];
  __shared__ __align__(16) ushort_t Bs[2][64][72];
  int j0 = blockIdx.x * 64;
  int m0 = blockIdx.y * 128;
  int tid = threadIdx.x;
  int lane = tid & 63, wv = tid >> 6;
  int l16 = lane & 15, qd = lane >> 4;
  f32x4 acc[2][4];
#pragma unroll
  for (int i=0;i<2;++i)
#pragma unroll
    for (int j=0;j<4;++j) acc[i][j] = (f32x4){0.f,0.f,0.f,0.f};

  const ushort_t* agp = aob + (long)m0*C_;
  const ushort_t* bgp = wpb + (long)j0*C_;

  {
    uint4 rA[4], rB[2];
#pragma unroll
    for (int i = 0; i < 4; ++i) {
      int idx = tid + 256*i;
      int row = idx >> 3, c8 = (idx & 7) << 3;
      rA[i] = *(const uint4*)(agp + (long)row*C_ + c8);
    }
    {
      int idx = tid, row = idx >> 3, c8 = (idx & 7) << 3;
      rB[0] = *(const uint4*)(bgp + (long)row*C_ + c8);
      idx = tid + 256; row = idx >> 3; c8 = (idx & 7) << 3;
      rB[1] = *(const uint4*)(bgp + (long)row*C_ + c8);
    }
#pragma unroll
    for (int i = 0; i < 4; ++i) {
      int idx = tid + 256*i;
      int row = idx >> 3, c8 = (idx & 7) << 3;
      *(uint4*)&As[0][row][c8] = rA[i];
    }
    {
      int idx = tid, row = idx >> 3, c8 = (idx & 7) << 3;
      *(uint4*)&Bs[0][row][c8] = rB[0];
      idx = tid + 256; row = idx >> 3; c8 = (idx & 7) << 3;
      *(uint4*)&Bs[0][row][c8] = rB[1];
    }
  }
  __syncthreads();

  for (int kt5 = 0; kt5 < 5; ++kt5) {
    const int cur = kt5 & 1, nxt = cur ^ 1;
    uint4 rA[4], rB[2];
    if (kt5 < 4) {
      int kn = kt5*64 + 64;
#pragma unroll
      for (int i = 0; i < 4; ++i) {
        int idx = tid + 256*i;
        int row = idx >> 3, c8 = (idx & 7) << 3;
        rA[i] = *(const uint4*)(agp + (long)row*C_ + kn + c8);
      }
      int idx = tid, row = idx >> 3, c8 = (idx & 7) << 3;
      rB[0] = *(const uint4*)(bgp + (long)row*C_ + kn + c8);
      idx = tid + 256; row = idx >> 3; c8 = (idx & 7) << 3;
      rB[1] = *(const uint4*)(bgp + (long)row*C_ + kn + c8);
    }
#pragma unroll
    for (int kb = 0; kb < 2; ++kb) {
      int ko = kb*32 + qd*8;
      f16x8 a0 = *(const f16x8*)&As[cur][wv*32 + l16][ko];
      f16x8 a1 = *(const f16x8*)&As[cur][wv*32 + 16 + l16][ko];
#pragma unroll
      for (int ct = 0; ct < 4; ++ct) {
        f16x8 b = *(const f16x8*)&Bs[cur][ct*16 + l16][ko];
        acc[0][ct] = __builtin_amdgcn_mfma_f32_16x16x32_f16(a0, b, acc[0][ct], 0,0,0);
        acc[1][ct] = __builtin_amdgcn_mfma_f32_16x16x32_f16(a1, b, acc[1][ct], 0,0,0);
      }
    }
    if (kt5 < 4) {
#pragma unroll
      for (int i = 0; i < 4; ++i) {
        int idx = tid + 256*i;
        int row = idx >> 3, c8 = (idx & 7) << 3;
        *(uint4*)&As[nxt][row][c8] = rA[i];
      }
      int idx = tid, row = idx >> 3, c8 = (idx & 7) << 3;
      *(uint4*)&Bs[nxt][row][c8] = rB[0];
      idx = tid + 256; row = idx >> 3; c8 = (idx & 7) << 3;
      *(uint4*)&Bs[nxt][row][c8] = rB[1];
    }
    __syncthreads();
  }
#pragma unroll
  for (int rt = 0; rt < 2; ++rt)
#pragma unroll
    for (int ct = 0; ct < 4; ++ct) {
      float bi = bias[j0 + ct*16 + l16];
#pragma unroll
      for (int r = 0; r < 4; ++r) {
        int m = m0 + wv*32 + rt*16 + qd*4 + r;
        out[(long)m*C_ + j0 + ct*16 + l16] = acc[rt][ct][r] + bi;
      }
    }
}

extern "C" void kernel_launch(void* const* d_in, const int* in_sizes, int n_in,
                              void* d_out, int out_size, void* d_ws, size_t ws_size,
                              hipStream_t stream) {
  const float* x      = (const float*)d_in[0];
  const float* ln_g   = (const float*)d_in[1];
  const float* ln_b   = (const float*)d_in[2];
  const float* qkv_w  = (const float*)d_in[3];
  const float* qkv_b  = (const float*)d_in[4];
  const float* proj_w = (const float*)d_in[5];
  const float* proj_b = (const float*)d_in[6];
  float* out = (float*)d_out;

  char* ws = (char*)d_ws;
  const long sz_bhnd = (long)B_*H_*N_*D_;   // 2,621,440
  ushort_t* xnb  = (ushort_t*)ws;                   ws += (long)M_*C_*2;
  ushort_t* aob  = (ushort_t*)ws;                   ws += (long)M_*C_*2;
  ushort_t* q    = (ushort_t*)ws;                   ws += sz_bhnd*2;
  ushort_t* k    = (ushort_t*)ws;                   ws += sz_bhnd*2;
  ushort_t* vt   = (ushort_t*)ws;                   ws += sz_bhnd*2;
  ushort_t* kb   = (ushort_t*)ws;                   ws += sz_bhnd*2;
  ushort_t* wqb  = (ushort_t*)ws;                   ws += (long)3*C_*C_*2;
  ushort_t* wpb  = (ushort_t*)ws;                   ws += (long)C_*C_*2;

  prep_kernel<<<2248, 256, 0, stream>>>(qkv_w, proj_w, x, ln_g, ln_b, wqb, wpb, xnb);
  qkvm_kernel<<<dim3(15, 64), 256, 0, stream>>>(xnb, wqb, qkv_b, q, k, vt);
  kb_kernel<<<dim3(16, B_*H_), 512, 0, stream>>>(k, kb);
  bsp_kernel<<<320, 256, 0, stream>>>(q, k, kb, vt, aob);
  projm_kernel<<<dim3(5, 64), 256, 0, stream>>>(aob, wpb, proj_b, out);
}

// Round 15
// 136.967 us; speedup vs baseline: 1.0367x; 1.0367x over previous
//
#include <hip/hip_runtime.h>
#include <math.h>

#define B_ 8
#define N_ 1024
#define C_ 320
#define H_ 5
#define D_ 64
#define M_ (B_*N_)

typedef unsigned short ushort_t;
typedef _Float16 half_t;
typedef __attribute__((ext_vector_type(2))) _Float16 h2;
typedef __attribute__((ext_vector_type(8))) _Float16 f16x8;
typedef __attribute__((ext_vector_type(4))) float f32x4;

// fp32 -> fp16 RNE, 1 VALU op (v_cvt_f16_f32)
__device__ __forceinline__ ushort_t f2h(float f) {
  union { half_t h; ushort_t u; } c; c.h = (half_t)f; return c.u;
}
// 2x fp32 -> packed fp16x2 RTZ, 1 VALU op (v_cvt_pkrtz_f16_f32)
__device__ __forceinline__ unsigned pkrtz(float a, float b) {
  auto r = __builtin_amdgcn_cvt_pkrtz(a, b);
  union { decltype(r) v; unsigned u; } c; c.v = r; return c.u;
}

// ------- prep: weight fp16 conversion + LayerNorm, one launch -------
__global__ __launch_bounds__(256) void prep_kernel(
    const float* __restrict__ qkv_w, const float* __restrict__ proj_w,
    const float* __restrict__ x, const float* __restrict__ gamma,
    const float* __restrict__ beta,
    ushort_t* __restrict__ wqb, ushort_t* __restrict__ wpb,
    ushort_t* __restrict__ xnb) {
  int bid = blockIdx.x;
  int tid = threadIdx.x;
  if (bid < 200) {
    const float* src = bid < 150 ? qkv_w : proj_w;
    ushort_t* dst    = bid < 150 ? wqb   : wpb;
    int base = (bid < 150 ? bid : bid - 150) * 2048;
    int idx = base + tid*8;
    float4 x0 = *(const float4*)(src+idx);
    float4 x1 = *(const float4*)(src+idx+4);
    unsigned pk[4] = {pkrtz(x0.x,x0.y), pkrtz(x0.z,x0.w),
                      pkrtz(x1.x,x1.y), pkrtz(x1.z,x1.w)};
    *(uint4*)(dst+idx) = *(const uint4*)pk;
  } else {
    int row = (bid - 200)*4 + (tid >> 6);
    int lane = tid & 63;
    const float* xr = x + (long)row * C_;
    float vals[5];
    float s = 0.f, ss = 0.f;
#pragma unroll
    for (int j = 0; j < 5; ++j) {
      float vv = xr[lane + 64*j];
      vals[j] = vv; s += vv; ss += vv*vv;
    }
#pragma unroll
    for (int o = 32; o > 0; o >>= 1) {
      s  += __shfl_xor(s, o, 64);
      ss += __shfl_xor(ss, o, 64);
    }
    float mean = s * (1.0f/C_);
    float var  = ss * (1.0f/C_) - mean*mean;
    float rstd = rsqrtf(var + 1e-5f);
    ushort_t* outr = xnb + (long)row * C_;
#pragma unroll
    for (int j = 0; j < 5; ++j) {
      int c = lane + 64*j;
      outr[c] = f2h((vals[j]-mean)*rstd*gamma[c] + beta[c]);
    }
  }
}

// ---------------- QKV GEMM via MFMA fp16: 128(M)x64(N) tile (r7-exact) ------
__global__ __launch_bounds__(256) void qkvm_kernel(const ushort_t* __restrict__ xnb,
    const ushort_t* __restrict__ wqb, const float* __restrict__ bias,
    ushort_t* __restrict__ q, ushort_t* __restrict__ k, ushort_t* __restrict__ vt) {
  __shared__ __align__(16) ushort_t As[128][72];
  __shared__ __align__(16) ushort_t Bs[64][72];
  __shared__ __align__(16) ushort_t Vs[64][136];
  int j0 = blockIdx.x * 64;
  int m0 = blockIdx.y * 128;
  int tid = threadIdx.x;
  int lane = tid & 63, wv = tid >> 6;
  int l16 = lane & 15, qd = lane >> 4;
  f32x4 acc[2][4];
#pragma unroll
  for (int i=0;i<2;++i)
#pragma unroll
    for (int j=0;j<4;++j) acc[i][j] = (f32x4){0.f,0.f,0.f,0.f};
  for (int kk = 0; kk < C_; kk += 64) {
#pragma unroll
    for (int i = 0; i < 4; ++i) {
      int idx = tid + 256*i;
      int row = idx >> 3, c8 = (idx & 7) << 3;
      *(uint4*)&As[row][c8] = *(const uint4*)(xnb + (long)(m0+row)*C_ + kk + c8);
    }
    {
      int idx = tid;
      int row = idx >> 3, c8 = (idx & 7) << 3;
      *(uint4*)&Bs[row][c8] = *(const uint4*)(wqb + (long)(j0+row)*C_ + kk + c8);
      idx = tid + 256; row = idx >> 3; c8 = (idx & 7) << 3;
      *(uint4*)&Bs[row][c8] = *(const uint4*)(wqb + (long)(j0+row)*C_ + kk + c8);
    }
    __syncthreads();
#pragma unroll
    for (int kb = 0; kb < 2; ++kb) {
      int ko = kb*32 + qd*8;
      f16x8 a0 = *(const f16x8*)&As[wv*32 + l16][ko];
      f16x8 a1 = *(const f16x8*)&As[wv*32 + 16 + l16][ko];
#pragma unroll
      for (int ct = 0; ct < 4; ++ct) {
        f16x8 b = *(const f16x8*)&Bs[ct*16 + l16][ko];
        acc[0][ct] = __builtin_amdgcn_mfma_f32_16x16x32_f16(a0, b, acc[0][ct], 0,0,0);
        acc[1][ct] = __builtin_amdgcn_mfma_f32_16x16x32_f16(a1, b, acc[1][ct], 0,0,0);
      }
    }
    __syncthreads();
  }
  int three = j0 / 320;
  int rembase = j0 - three*320;
  if (three < 2) {
    ushort_t* dst = three == 0 ? q : k;
    float scale = three == 0 ? 0.125f : 1.0f;
#pragma unroll
    for (int rt = 0; rt < 2; ++rt)
#pragma unroll
      for (int ct = 0; ct < 4; ++ct) {
        int rem = rembase + ct*16 + l16;
        int h = rem >> 6, dd = rem & 63;
        float bi = bias[j0 + ct*16 + l16];
#pragma unroll
        for (int r = 0; r < 4; ++r) {
          int m = m0 + wv*32 + rt*16 + qd*4 + r;
          int b = m >> 10, n = m & (N_-1);
          dst[(((long)b*H_ + h)*N_ + n)*D_ + dd] = f2h((acc[rt][ct][r] + bi) * scale);
        }
      }
  } else {
    int h = rembase >> 6;
#pragma unroll
    for (int rt = 0; rt < 2; ++rt)
#pragma unroll
      for (int ct = 0; ct < 4; ++ct) {
        float bi = bias[j0 + ct*16 + l16];
#pragma unroll
        for (int r = 0; r < 4; ++r) {
          int col = wv*32 + rt*16 + qd*4 + r;
          Vs[ct*16 + l16][col] = f2h(acc[rt][ct][r] + bi);
        }
      }
    __syncthreads();
    int b = m0 >> 10, n0b = m0 & (N_-1);
#pragma unroll
    for (int i = 0; i < 4; ++i) {
      int idx = tid + 256*i;
      int row = idx >> 4, c8 = (idx & 15) << 3;
      *(uint4*)(vt + (((long)b*H_ + h)*D_ + row)*N_ + n0b + c8) = *(const uint4*)&Vs[row][c8];
    }
  }
}

// ------- qb: separable-blur factor precompute (r7-exact) -------
// blur2d(Q K^T) = (blur_n Q) (blur_n K)^T  (w outer w, linear in S).
// qb = w-blur of q along n (reflect); kb = alpha * w-blur of k along n.
__global__ __launch_bounds__(512) void qb_kernel(
    const ushort_t* __restrict__ q, const ushort_t* __restrict__ kk,
    ushort_t* __restrict__ qb, ushort_t* __restrict__ kb) {
  int bh = blockIdx.y;
  int h = bh % H_;
  int r = blockIdx.x*64 + (threadIdx.x >> 3);
  int d8 = (threadIdx.x & 7) << 3;
  float sigma = (float)(h + 1);
  float ei = -1.f / (2.f * sigma * sigma);
  float ga = expf(9.f*ei), gb = expf(4.f*ei), gc = expf(1.f*ei);
  float isum = 1.f / (2.f*(ga + gb + gc) + 1.f);
  float alpha = 0.1f * sigma;
  const float w[7] = {ga*isum, gb*isum, gc*isum, isum, gc*isum, gb*isum, ga*isum};
  const ushort_t* qb_base = q  + (long)bh*N_*D_ + d8;
  const ushort_t* kb_base = kk + (long)bh*N_*D_ + d8;
  float aq[8] = {0,0,0,0,0,0,0,0};
  float ak[8] = {0,0,0,0,0,0,0,0};
#pragma unroll
  for (int t = 0; t < 7; ++t) {
    int p = r + t - 3;
    int rr = p < 0 ? -p : (p > N_-1 ? 2*(N_-1)-p : p);
    union { uint4 v; h2 hh[4]; } uq, uk;
    uq.v = *(const uint4*)(qb_base + (long)rr*D_);
    uk.v = *(const uint4*)(kb_base + (long)rr*D_);
    float wt = w[t];
#pragma unroll
    for (int j = 0; j < 4; ++j) {
      aq[2*j]   += wt * (float)uq.hh[j].x;
      aq[2*j+1] += wt * (float)uq.hh[j].y;
      ak[2*j]   += wt * (float)uk.hh[j].x;
      ak[2*j+1] += wt * (float)uk.hh[j].y;
    }
  }
  ushort_t pq[8], pk[8];
#pragma unroll
  for (int j = 0; j < 8; ++j) {
    pq[j] = f2h(aq[j]);
    pk[j] = f2h(ak[j] * alpha);
  }
  long ooff = ((long)bh*N_ + r)*D_ + d8;
  *(uint4*)(qb + ooff) = *(const uint4*)pq;
  *(uint4*)(kb + ooff) = *(const uint4*)pk;
}

// ------- Flash fused logits + softmax + PV (v19, r12-exact best: 138.3us) ---
// 32 q/wave (two Q-fragment sets): every K/Kb fragment read feeds 8 MFMAs,
// every V fragment feeds 2 accumulator sets. r7 chunk schedule: {issue
// next-chunk global->reg loads, compute, ds_write staged regs, ONE barrier}.
// 4 waves, 128 q/block, grid 320, XCD-bijective swizzle.
__global__ __launch_bounds__(256, 2) void bsp_kernel(
    const ushort_t* __restrict__ q,  const ushort_t* __restrict__ qbb,
    const ushort_t* __restrict__ kk, const ushort_t* __restrict__ kb,
    const ushort_t* __restrict__ vt, ushort_t* __restrict__ aob) {
  __shared__ __align__(16) ushort_t Ks[2][64][72];
  __shared__ __align__(16) ushort_t Bs[2][64][72];
  __shared__ __align__(16) ushort_t Vs[2][64][72];
  __shared__ __align__(16) ushort_t Pb[4][32][72];

  int lin = blockIdx.x;
  int lin2 = (lin & 7)*40 + (lin >> 3);   // bijective: 320 = 8*40
  int bh = lin2 >> 3;
  int qblk = lin2 & 7;
  int h = bh % H_;
  int bb = bh / H_;
  int tid = threadIdx.x;
  int wv = tid >> 6, lane = tid & 63;
  int l16 = lane & 15, qd = lane >> 4;
  int qbase = qblk*128 + wv*32;

  int srow = tid >> 3, sc8 = (tid & 7) << 3;
  const ushort_t* kgp = kk + (long)bh*N_*D_ + (long)srow*D_ + sc8;
  const ushort_t* bgp = kb + (long)bh*N_*D_ + (long)srow*D_ + sc8;
  const ushort_t* vgp = vt + (long)bh*D_*N_ + (long)srow*N_ + sc8;

  long qoffA = ((long)bh*N_ + qbase + l16)*D_ + qd*8;
  long qoffB = ((long)bh*N_ + qbase + 16 + l16)*D_ + qd*8;
  f16x8 bqA0 = *(const f16x8*)(q   + qoffA);
  f16x8 bqA1 = *(const f16x8*)(q   + qoffA + 32);
  f16x8 bqA2 = *(const f16x8*)(qbb + qoffA);
  f16x8 bqA3 = *(const f16x8*)(qbb + qoffA + 32);
  f16x8 bqB0 = *(const f16x8*)(q   + qoffB);
  f16x8 bqB1 = *(const f16x8*)(q   + qoffB + 32);
  f16x8 bqB2 = *(const f16x8*)(qbb + qoffB);
  f16x8 bqB3 = *(const f16x8*)(qbb + qoffB + 32);

  ushort_t (*Pw)[72] = Pb[wv];
  float rsum0 = 0.f, rsum1 = 0.f;
  f32x4 oaA[4], oaB[4];
#pragma unroll
  for (int dt = 0; dt < 4; ++dt) {
    oaA[dt] = (f32x4){0.f,0.f,0.f,0.f};
    oaB[dt] = (f32x4){0.f,0.f,0.f,0.f};
  }

  *(uint4*)&Ks[0][srow][sc8]    = *(const uint4*)(kgp);
  *(uint4*)&Ks[0][srow+32][sc8] = *(const uint4*)(kgp + 32*D_);
  *(uint4*)&Bs[0][srow][sc8]    = *(const uint4*)(bgp);
  *(uint4*)&Bs[0][srow+32][sc8] = *(const uint4*)(bgp + 32*D_);
  *(uint4*)&Vs[0][srow][sc8]    = *(const uint4*)(vgp);
  *(uint4*)&Vs[0][srow+32][sc8] = *(const uint4*)(vgp + 32*N_);
  __syncthreads();

  for (int ch = 0; ch < 16; ++ch) {
    const int cur = ch & 1, nxt = cur ^ 1;
    uint4 gk0, gk1, gb0, gb1, gv0, gv1;
    if (ch < 15) {
      long c1 = (long)(ch + 1) * 64;
      gk0 = *(const uint4*)(kgp + c1*D_);
      gk1 = *(const uint4*)(kgp + (c1+32)*D_);
      gb0 = *(const uint4*)(bgp + c1*D_);
      gb1 = *(const uint4*)(bgp + (c1+32)*D_);
      gv0 = *(const uint4*)(vgp + c1);
      gv1 = *(const uint4*)(vgp + 32*N_ + c1);
    }
#pragma unroll
    for (int kt = 0; kt < 4; ++kt) {
      int r = kt*16 + l16;
      f16x8 a0 = *(const f16x8*)&Ks[cur][r][qd*8];
      f16x8 a1 = *(const f16x8*)&Ks[cur][r][qd*8 + 32];
      f16x8 a2 = *(const f16x8*)&Bs[cur][r][qd*8];
      f16x8 a3 = *(const f16x8*)&Bs[cur][r][qd*8 + 32];
      f32x4 s0 = (f32x4){0.f,0.f,0.f,0.f};
      f32x4 s1 = (f32x4){0.f,0.f,0.f,0.f};
      s0 = __builtin_amdgcn_mfma_f32_16x16x32_f16(a0, bqA0, s0, 0,0,0);
      s1 = __builtin_amdgcn_mfma_f32_16x16x32_f16(a0, bqB0, s1, 0,0,0);
      s0 = __builtin_amdgcn_mfma_f32_16x16x32_f16(a1, bqA1, s0, 0,0,0);
      s1 = __builtin_amdgcn_mfma_f32_16x16x32_f16(a1, bqB1, s1, 0,0,0);
      s0 = __builtin_amdgcn_mfma_f32_16x16x32_f16(a2, bqA2, s0, 0,0,0);
      s1 = __builtin_amdgcn_mfma_f32_16x16x32_f16(a2, bqB2, s1, 0,0,0);
      s0 = __builtin_amdgcn_mfma_f32_16x16x32_f16(a3, bqA3, s0, 0,0,0);
      s1 = __builtin_amdgcn_mfma_f32_16x16x32_f16(a3, bqB3, s1, 0,0,0);
      float e0 = __expf(s0[0]), e1 = __expf(s0[1]);
      float e2 = __expf(s0[2]), e3 = __expf(s0[3]);
      float f0 = __expf(s1[0]), f1 = __expf(s1[1]);
      float f2 = __expf(s1[2]), f3 = __expf(s1[3]);
      rsum0 += (e0 + e1) + (e2 + e3);
      rsum1 += (f0 + f1) + (f2 + f3);
      *(uint2*)&Pw[l16][kt*16 + qd*4]      = make_uint2(pkrtz(e0,e1), pkrtz(e2,e3));
      *(uint2*)&Pw[16 + l16][kt*16 + qd*4] = make_uint2(pkrtz(f0,f1), pkrtz(f2,f3));
    }
#pragma unroll
    for (int ks = 0; ks < 2; ++ks) {
      f16x8 af0 = *(const f16x8*)&Pw[l16][ks*32 + qd*8];
      f16x8 af1 = *(const f16x8*)&Pw[16 + l16][ks*32 + qd*8];
#pragma unroll
      for (int dt = 0; dt < 4; ++dt) {
        f16x8 bf = *(const f16x8*)&Vs[cur][dt*16 + l16][ks*32 + qd*8];
        oaA[dt] = __builtin_amdgcn_mfma_f32_16x16x32_f16(af0, bf, oaA[dt], 0,0,0);
        oaB[dt] = __builtin_amdgcn_mfma_f32_16x16x32_f16(af1, bf, oaB[dt], 0,0,0);
      }
    }
    if (ch < 15) {
      *(uint4*)&Ks[nxt][srow][sc8]    = gk0;
      *(uint4*)&Ks[nxt][srow+32][sc8] = gk1;
      *(uint4*)&Bs[nxt][srow][sc8]    = gb0;
      *(uint4*)&Bs[nxt][srow+32][sc8] = gb1;
      *(uint4*)&Vs[nxt][srow][sc8]    = gv0;
      *(uint4*)&Vs[nxt][srow+32][sc8] = gv1;
    }
    __syncthreads();
  }

  rsum0 += __shfl_xor(rsum0, 16, 64);
  rsum0 += __shfl_xor(rsum0, 32, 64);
  rsum1 += __shfl_xor(rsum1, 16, 64);
  rsum1 += __shfl_xor(rsum1, 32, 64);
  float rinv0 = 1.f / rsum0;
  float rinv1 = 1.f / rsum1;
  float rv0[4], rv1[4];
#pragma unroll
  for (int r = 0; r < 4; ++r) {
    rv0[r] = __shfl(rinv0, qd*4 + r, 64);
    rv1[r] = __shfl(rinv1, qd*4 + r, 64);
  }
#pragma unroll
  for (int dt = 0; dt < 4; ++dt)
#pragma unroll
    for (int r = 0; r < 4; ++r) {
      aob[((long)(bb*N_ + qbase + qd*4 + r))*C_ + h*64 + dt*16 + l16] =
          f2h(oaA[dt][r] * rv0[r]);
      aob[((long)(bb*N_ + qbase + 16 + qd*4 + r))*C_ + h*64 + dt*16 + l16] =
          f2h(oaB[dt][r] * rv1[r]);
    }
}

// ---------------- proj GEMM via MFMA fp16: 128(M)x64(N) tile (r7-exact) -----
__global__ __launch_bounds__(256) void projm_kernel(const ushort_t* __restrict__ aob,
    const ushort_t* __restrict__ wpb, const float* __restrict__ bias,
    float* __restrict__ out) {
  __shared__ __align__(16) ushort_t As[128][72];
  __shared__ __align__(16) ushort_t Bs[64][72];
  int j0 = blockIdx.x * 64;
  int m0 = blockIdx.y * 128;
  int tid = threadIdx.x;
  int lane = tid & 63, wv = tid >> 6;
  int l16 = lane & 15, qd = lane >> 4;
  f32x4 acc[2][4];
#pragma unroll
  for (int i=0;i<2;++i)
#pragma unroll
    for (int j=0;j<4;++j) acc[i][j] = (f32x4){0.f,0.f,0.f,0.f};
  for (int kk = 0; kk < C_; kk += 64) {
#pragma unroll
    for (int i = 0; i < 4; ++i) {
      int idx = tid + 256*i;
      int row = idx >> 3, c8 = (idx & 7) << 3;
      *(uint4*)&As[row][c8] = *(const uint4*)(aob + (long)(m0+row)*C_ + kk + c8);
    }
    {
      int idx = tid;
      int row = idx >> 3, c8 = (idx & 7) << 3;
      *(uint4*)&Bs[row][c8] = *(const uint4*)(wpb + (long)(j0+row)*C_ + kk + c8);
      idx = tid + 256; row = idx >> 3; c8 = (idx & 7) << 3;
      *(uint4*)&Bs[row][c8] = *(const uint4*)(wpb + (long)(j0+row)*C_ + kk + c8);
    }
    __syncthreads();
#pragma unroll
    for (int kb = 0; kb < 2; ++kb) {
      int ko = kb*32 + qd*8;
      f16x8 a0 = *(const f16x8*)&As[wv*32 + l16][ko];
      f16x8 a1 = *(const f16x8*)&As[wv*32 + 16 + l16][ko];
#pragma unroll
      for (int ct = 0; ct < 4; ++ct) {
        f16x8 b = *(const f16x8*)&Bs[ct*16 + l16][ko];
        acc[0][ct] = __builtin_amdgcn_mfma_f32_16x16x32_f16(a0, b, acc[0][ct], 0,0,0);
        acc[1][ct] = __builtin_amdgcn_mfma_f32_16x16x32_f16(a1, b, acc[1][ct], 0,0,0);
      }
    }
    __syncthreads();
  }
#pragma unroll
  for (int rt = 0; rt < 2; ++rt)
#pragma unroll
    for (int ct = 0; ct < 4; ++ct) {
      float bi = bias[j0 + ct*16 + l16];
#pragma unroll
      for (int r = 0; r < 4; ++r) {
        int m = m0 + wv*32 + rt*16 + qd*4 + r;
        out[(long)m*C_ + j0 + ct*16 + l16] = acc[rt][ct][r] + bi;
      }
    }
}

extern "C" void kernel_launch(void* const* d_in, const int* in_sizes, int n_in,
                              void* d_out, int out_size, void* d_ws, size_t ws_size,
                              hipStream_t stream) {
  const float* x      = (const float*)d_in[0];
  const float* ln_g   = (const float*)d_in[1];
  const float* ln_b   = (const float*)d_in[2];
  const float* qkv_w  = (const float*)d_in[3];
  const float* qkv_b  = (const float*)d_in[4];
  const float* proj_w = (const float*)d_in[5];
  const float* proj_b = (const float*)d_in[6];
  float* out = (float*)d_out;

  char* ws = (char*)d_ws;
  const long sz_bhnd = (long)B_*H_*N_*D_;   // 2,621,440
  ushort_t* xnb  = (ushort_t*)ws;                   ws += (long)M_*C_*2;
  ushort_t* aob  = (ushort_t*)ws;                   ws += (long)M_*C_*2;
  ushort_t* q    = (ushort_t*)ws;                   ws += sz_bhnd*2;
  ushort_t* k    = (ushort_t*)ws;                   ws += sz_bhnd*2;
  ushort_t* vt   = (ushort_t*)ws;                   ws += sz_bhnd*2;
  ushort_t* qb   = (ushort_t*)ws;                   ws += sz_bhnd*2;
  ushort_t* kb   = (ushort_t*)ws;                   ws += sz_bhnd*2;
  ushort_t* wqb  = (ushort_t*)ws;                   ws += (long)3*C_*C_*2;
  ushort_t* wpb  = (ushort_t*)ws;                   ws += (long)C_*C_*2;

  prep_kernel<<<2248, 256, 0, stream>>>(qkv_w, proj_w, x, ln_g, ln_b, wqb, wpb, xnb);
  qkvm_kernel<<<dim3(15, 64), 256, 0, stream>>>(xnb, wqb, qkv_b, q, k, vt);
  qb_kernel<<<dim3(16, B_*H_), 512, 0, stream>>>(q, k, qb, kb);
  bsp_kernel<<<320, 256, 0, stream>>>(q, qb, k, kb, vt, aob);
  projm_kernel<<<dim3(5, 64), 256, 0, stream>>>(aob, wpb, proj_b, out);
}